// Round 3
// baseline (212.288 us; speedup 1.0000x reference)
//
#include <hip/hip_runtime.h>
#include <hip/hip_bf16.h>
#include <math.h>

#define BB 4
#define CC 64
#define HH 128
#define WW 128
#define HW (HH*WW)          // 16384
#define NPIX (BB*HW)        // 65536

typedef __attribute__((ext_vector_type(8))) short short8;   // 8 bf16
typedef __attribute__((ext_vector_type(4))) float f32x4;

__device__ __forceinline__ float bf2f(ushort u) {
  union { unsigned u; float f; } v; v.u = ((unsigned)u) << 16; return v.f;
}
__device__ __forceinline__ ushort f2bf(float f) {
  __hip_bfloat16 h = __float2bfloat16(f); return *(ushort*)&h;
}

// ---------------------------------------------------------------------------
// Prep (unchanged): NCHW fp32 -> channels-last bf16 + weights.
// ---------------------------------------------------------------------------
__global__ __launch_bounds__(256) void k_prep(
    const float* __restrict__ x, const float* __restrict__ inter,
    const float* __restrict__ w_off, const float* __restrict__ w_dcn,
    const float* __restrict__ wg1, const float* __restrict__ wb1,
    const float* __restrict__ wg2, const float* __restrict__ wb2,
    ushort* __restrict__ x_clh, ushort* __restrict__ inter_clh,
    ushort* __restrict__ wfb, ushort* __restrict__ wdT,
    ushort* __restrict__ w1gb, ushort* __restrict__ w1bb,
    ushort* __restrict__ w2gb, ushort* __restrict__ w2bb,
    float* __restrict__ zp) {
  __shared__ __align__(16) float tile[64 * 128];   // 32 KiB, xor-swizzled
  int blk = blockIdx.x;
  int tid = threadIdx.x;
  if (blk < 1024) {
    int sel = blk >> 9;
    int bh = blk & 511;
    int b = bh >> 7, h = bh & 127;
    const float* src = sel ? inter : x;
    ushort* dst = sel ? inter_clh : x_clh;
    const float* sp = src + (size_t)(b * 64) * HW + h * WW;
#pragma unroll
    for (int it = 0; it < 8; ++it) {
      int idx = it * 256 + tid;
      int c = idx >> 5, wq = idx & 31;
      float4 v = *(const float4*)(sp + (size_t)c * HW + wq * 4);
      int s = (c >> 3) & 7;
      *(float4*)(&tile[c * 128 + ((wq ^ s) << 2)]) = v;
    }
    __syncthreads();
    ushort* dp = dst + ((size_t)b * HW + h * WW) * 64;
#pragma unroll
    for (int it = 0; it < 4; ++it) {
      int idx = it * 256 + tid;
      int w = idx >> 3, c8 = idx & 7;
      short8 outv;
#pragma unroll
      for (int j = 0; j < 8; ++j) {
        int c = c8 * 8 + j;
        int sl = (w >> 2) ^ c8;
        float f = tile[c * 128 + (sl << 2) + (w & 3)];
        outv[j] = (short)f2bf(f);
      }
      *(short8*)(dp + (size_t)w * 64 + c8 * 8) = outv;
    }
  } else if (blk < 1168) {
    int i = (blk - 1024) * 256 + tid;
    if (i < 64) zp[i] = 0.f;
    if (i < 9 * 32 * 128) {
      int tap = i >> 12, rem = i & 4095, m = rem >> 7, c = rem & 127;
      float v = (m < 27) ? w_off[(size_t)(m * 128 + c) * 9 + tap] : 0.f;
      wfb[i] = f2bf(v);
    }
  } else if (blk < 1312) {
    int i = (blk - 1168) * 256 + tid;
    if (i < 64 * 64 * 9) {
      int o = i / 576, rem = i % 576, k = rem >> 6, c = rem & 63;
      wdT[i] = f2bf(w_dcn[(o * 64 + c) * 9 + k]);
    }
  } else {
    int i = (blk - 1312) * 256 + tid;   // 0..16383
    int m = i >> 12, j = i & 4095;
    const float* src = (m == 0) ? wg1 : (m == 1) ? wb1 : (m == 2) ? wg2 : wb2;
    ushort* dst = (m == 0) ? w1gb : (m == 1) ? w1bb : (m == 2) ? w2gb : w2bb;
    dst[j] = f2bf(src[j]);
  }
}

// ---------------------------------------------------------------------------
// OMEGA v3.1: v3 with the conv B-frag channel-slice bug fixed (+ quad*8).
// Target 8 blocks/CU (single residency round of the 2048-block grid)
// + small icache footprint (rolled loops) + XCD-local work swizzle.
//  - NO conv halo staging: conv B-frags are per-lane 16B loads straight from
//    x_clh/inter_clh (channels-last), zero-page select for borders.
//  - LDS total 19584 B -> 8 blocks/CU. VGPR capped 64 via launch_bounds(256,8).
//  - gamma/beta folded into epilogue vector ev right after phase 4.
//  - sigmoid(mask) stored in-place in oml m-rows; coords packed (cy|cx).
//  - chunk/it/ky loops rolled (#pragma unroll 1): code ~4x smaller.
// LDS layout (shorts; 9792 shorts = 19584 B):
//   [0,6272)     S  32px x 196 (phase 6)   | Sg[0,2304) Sb[2304,4608) (ph 3-4)
//   [6272,6848)  cycx packed int  (ph 5-6)
//   [6848,7424)  cwy f32          (ph 5-6)
//   [7424,8000)  cwx f32          (ph 5-6)
//   [8000,9782)  oml f32 27x33    (ph 2-6; rows 18-26 become sigmoid(m))
// ---------------------------------------------------------------------------
#define SPITCH 196   // shorts per pixel row in gather buffer S
#define NPX 32       // pixels per block
#define FPX 72       // shorts per px row in Sg/Sb

__global__ __launch_bounds__(256, 8) void k_omega(
    const float* __restrict__ x, const ushort* __restrict__ x_clh,
    const ushort* __restrict__ inter_clh,
    const float* __restrict__ b_off, const ushort* __restrict__ wfb,
    const ushort* __restrict__ wdT,
    const ushort* __restrict__ w1gb, const ushort* __restrict__ w1bb,
    const ushort* __restrict__ w2gb, const ushort* __restrict__ w2bb,
    const ushort* __restrict__ zp16, float* __restrict__ out) {
  __shared__ __align__(16) ushort LDSB[9792];          // 19584 B
  ushort* S  = LDSB;                                    // phase 6
  ushort* Sg = LDSB;                                    // phases 3-4
  ushort* Sb = LDSB + NPX * FPX;                        // 2304..4608
  int*   cycx = (int*)(LDSB + 6272);                    // 288 packed coords
  float* cwy  = (float*)(LDSB + 6848);
  float* cwx  = (float*)(LDSB + 7424);
  float* oml  = (float*)(LDSB + 8000);                  // 27 x 33 f32

  int tid = threadIdx.x;
  int wave = tid >> 6, lane = tid & 63;
  int quad = lane >> 4, col = lane & 15;
  int rr = lane >> 3, g = lane & 7;
  // XCD-local swizzle: 2048 blocks, 8 XCDs -> each XCD owns 256 consecutive
  // work ids (same-b, adjacent-h rows share gather/conv panels in its L2).
  int bid = blockIdx.x;
  int wid = (bid & 7) * 256 + (bid >> 3);
  int pg0 = wid * NPX;
  int b = pg0 >> 14, hw0 = pg0 & 16383;
  int h = hw0 >> 7, w0 = hw0 & 127;
  int pt = wave >> 1, mt = wave & 1;
  int o_base = __builtin_amdgcn_readfirstlane(wave * 16);

  // ---- phase 2: conv MFMAs, B-frags direct from global (no LDS halo) ----
  f32x4 accx = {0.f, 0.f, 0.f, 0.f}, acci = {0.f, 0.f, 0.f, 0.f};
  {
    const ushort* wb0 = wfb + (size_t)(mt * 16 + col) * 128 + quad * 8;
    int pxcol = pt * 16 + col;
    unsigned bbase = (unsigned)b * HW;
#pragma unroll 1
    for (int ky = 0; ky < 3; ++ky) {
      int hs = h + ky - 1;
      bool oky = (unsigned)hs < 128u;
      int rowb = hs << 7;
#pragma unroll
      for (int kx = 0; kx < 3; ++kx) {
        int ws = w0 + pxcol + kx - 1;
        bool ok = oky && ((unsigned)ws < 128u);
        long long poff = (long long)(int)(bbase + rowb + ws) * 64;
        // per-lane channel slice: ks*32 + quad*8 (THE round-2 bug was
        // dropping quad*8 here; zp page is 128 zero shorts, max off 64+8 ok)
        const ushort* bx = (ok ? x_clh + poff : zp16) + quad * 8;
        const ushort* bi = (ok ? inter_clh + poff : zp16) + quad * 8;
        const ushort* wt = wb0 + (size_t)(ky * 3 + kx) * 4096;
#pragma unroll
        for (int ks = 0; ks < 2; ++ks) {
          short8 a0 = *(const short8*)(wt + ks * 32);
          short8 b0 = *(const short8*)(bx + ks * 32);
          accx = __builtin_amdgcn_mfma_f32_16x16x32_bf16(a0, b0, accx, 0, 0, 0);
          short8 a1 = *(const short8*)(wt + 64 + ks * 32);
          short8 b1 = *(const short8*)(bi + ks * 32);
          acci = __builtin_amdgcn_mfma_f32_16x16x32_bf16(a1, b1, acci, 0, 0, 0);
        }
      }
    }
  }
  // om -> LDS (consumed in phase 5, after B1).
#pragma unroll
  for (int r = 0; r < 4; ++r) {
    int o = mt * 16 + quad * 4 + r;
    if (o < 27) oml[o * 33 + pt * 16 + col] = accx[r] + acci[r];
  }

  // ---- phase 3: SFT stage A -> Sg/Sb ----
  f32x4 ag[2], ab[2];
#pragma unroll
  for (int nt = 0; nt < 2; ++nt) {
    ag[nt] = (f32x4){0.f, 0.f, 0.f, 0.f};
    ab[nt] = (f32x4){0.f, 0.f, 0.f, 0.f};
  }
#pragma unroll
  for (int ks = 0; ks < 2; ++ks) {
    short8 a_g = *(const short8*)(w1gb + (size_t)(o_base + col) * 64 + ks * 32 + quad * 8);
    short8 a_b = *(const short8*)(w1bb + (size_t)(o_base + col) * 64 + ks * 32 + quad * 8);
#pragma unroll
    for (int nt = 0; nt < 2; ++nt) {
      short8 bf = *(const short8*)(inter_clh + (size_t)(pg0 + nt * 16 + col) * 64 + ks * 32 + quad * 8);
      ag[nt] = __builtin_amdgcn_mfma_f32_16x16x32_bf16(a_g, bf, ag[nt], 0, 0, 0);
      ab[nt] = __builtin_amdgcn_mfma_f32_16x16x32_bf16(a_b, bf, ab[nt], 0, 0, 0);
    }
  }
#pragma unroll
  for (int nt = 0; nt < 2; ++nt) {
    int px = nt * 16 + col;
    ushort pkg[4], pkb[4];
#pragma unroll
    for (int r = 0; r < 4; ++r) {
      float vg = ag[nt][r]; vg = vg >= 0.f ? vg : 0.1f * vg;
      float vb = ab[nt][r]; vb = vb >= 0.f ? vb : 0.1f * vb;
      pkg[r] = f2bf(vg); pkb[r] = f2bf(vb);
    }
    *(uint2*)(&Sg[px * FPX + o_base + quad * 4]) = *(uint2*)pkg;
    *(uint2*)(&Sb[px * FPX + o_base + quad * 4]) = *(uint2*)pkb;
  }
  __syncthreads();   // B1: oml + Sg/Sb visible

  // ---- phase 4: SFT stage B; fold gamma/beta+x into epilogue vector ev ----
  f32x4 gg[2], gb[2];
#pragma unroll
  for (int nt = 0; nt < 2; ++nt) {
    gg[nt] = (f32x4){0.f, 0.f, 0.f, 0.f};
    gb[nt] = (f32x4){0.f, 0.f, 0.f, 0.f};
  }
#pragma unroll
  for (int ks = 0; ks < 2; ++ks) {
    short8 a_g = *(const short8*)(w2gb + (size_t)(o_base + col) * 64 + ks * 32 + quad * 8);
    short8 a_b = *(const short8*)(w2bb + (size_t)(o_base + col) * 64 + ks * 32 + quad * 8);
#pragma unroll
    for (int nt = 0; nt < 2; ++nt) {
      short8 bgf = *(const short8*)(Sg + (nt * 16 + col) * FPX + ks * 32 + quad * 8);
      short8 bbf = *(const short8*)(Sb + (nt * 16 + col) * FPX + ks * 32 + quad * 8);
      gg[nt] = __builtin_amdgcn_mfma_f32_16x16x32_bf16(a_g, bgf, gg[nt], 0, 0, 0);
      gb[nt] = __builtin_amdgcn_mfma_f32_16x16x32_bf16(a_b, bbf, gb[nt], 0, 0, 0);
    }
  }
  float ev[2][4];
#pragma unroll
  for (int nt = 0; nt < 2; ++nt)
#pragma unroll
    for (int r = 0; r < 4; ++r) {
      int o = o_base + quad * 4 + r;
      float xv = x[(size_t)(b * 64 + o) * HW + hw0 + nt * 16 + col];
      ev[nt][r] = xv + xv * gg[nt][r] + gb[nt][r];
    }

  // ---- phase 5: coords (packed) + sigmoid(m) in-place in oml ----
  // Writes coord region + oml m-rows only; disjoint from Sg/Sb phase-4 reads.
  for (int i = tid; i < 9 * NPX; i += 256) {
    int k = i >> 5, p = i & 31;
    float dy = oml[k * 33 + p] + b_off[k];
    float dx = oml[(9 + k) * 33 + p] + b_off[9 + k];
    float mz = oml[(18 + k) * 33 + p] + b_off[18 + k];
    float py = (float)(h + (k / 3) - 1) + dy;
    float px = (float)(w0 + p + (k % 3) - 1) + dx;
    float y0f = floorf(py), x0f = floorf(px);
    int iy = (int)y0f, ix = (int)x0f;
    cycx[i] = (iy & 0xffff) | (ix << 16);
    cwy[i] = py - y0f;
    cwx[i] = px - x0f;
    oml[(18 + k) * 33 + p] = 1.f / (1.f + __expf(-mz));
  }

  f32x4 acc[2];
  acc[0] = (f32x4){0.f, 0.f, 0.f, 0.f};
  acc[1] = (f32x4){0.f, 0.f, 0.f, 0.f};

  const ushort* bp = x_clh + (size_t)b * HW * 64;
  int p = wave * 8 + rr;

  // ---- phase 6: gather + MFMA chunks (rolled) ----
#pragma unroll 1
  for (int chunk = 0; chunk < 3; ++chunk) {
    __syncthreads();   // chunk 0: coords ready + phase-4 Sg/Sb reads done
#pragma unroll 1
    for (int it = 0; it < 3; ++it) {
      int k = chunk * 3 + it;
      int idx = k * 32 + p;
      int v = cycx[idx];
      int y0 = (int)(short)(v & 0xffff);
      int x0 = v >> 16;
      float wy = cwy[idx], wx = cwx[idx];
      float m = oml[(18 + k) * 33 + p];
      bool yok0 = (unsigned)y0 < 128u, yok1 = (unsigned)(y0 + 1) < 128u;
      bool xok0 = (unsigned)x0 < 128u, xok1 = (unsigned)(x0 + 1) < 128u;
      const ushort* r0 = bp + ((size_t)(int)((y0 << 7) + x0)) * 64 + g * 8;
      const ushort* r1 = r0 + (size_t)WW * 64;
      short8 s00 = *(const short8*)((yok0 && xok0) ? r0 : zp16);
      short8 s01 = *(const short8*)((yok0 && xok1) ? (r0 + 64) : zp16);
      short8 s10 = *(const short8*)((yok1 && xok0) ? r1 : zp16);
      short8 s11 = *(const short8*)((yok1 && xok1) ? (r1 + 64) : zp16);
      short8 outv;
#pragma unroll
      for (int j = 0; j < 8; ++j) {
        float v00 = bf2f((ushort)s00[j]), v01 = bf2f((ushort)s01[j]);
        float v10 = bf2f((ushort)s10[j]), v11 = bf2f((ushort)s11[j]);
        float top = v00 + (v01 - v00) * wx;
        float bot = v10 + (v11 - v10) * wx;
        float val = top + (bot - top) * wy;
        outv[j] = (short)f2bf(val * m);
      }
      *(short8*)(&S[p * SPITCH + it * 64 + g * 8]) = outv;
    }
    __syncthreads();
    const ushort* wrow = wdT + (size_t)(o_base + col) * 576 + chunk * 192 + quad * 8;
    const ushort* srow = S + quad * 8;
#pragma unroll
    for (int ks = 0; ks < 6; ++ks) {
      short8 a = *(const short8*)(wrow + ks * 32);
#pragma unroll
      for (int nt = 0; nt < 2; ++nt) {
        short8 bf = *(const short8*)(srow + (nt * 16 + col) * SPITCH + ks * 32);
        acc[nt] = __builtin_amdgcn_mfma_f32_16x16x32_bf16(a, bf, acc[nt], 0, 0, 0);
      }
    }
  }

  // ---- phase 7: epilogue: out = ev + dcn (single write) ----
#pragma unroll
  for (int nt = 0; nt < 2; ++nt) {
#pragma unroll
    for (int r = 0; r < 4; ++r) {
      int o = o_base + quad * 4 + r;
      size_t idx = (size_t)(b * 64 + o) * HW + hw0 + nt * 16 + col;
      out[idx] = ev[nt][r] + acc[nt][r];
    }
  }
}

// ---------------------------------------------------------------------------
// Workspace plan (float slots), all concurrent (~17 MB):
//   x_clh     ushort [0        .. 2097152)
//   inter_clh ushort [2097152  .. 4194304)
//   wfb       ushort [5963776  .. 5982208)
//   wdT       ushort [5982208  .. 6000640)
//   w1gb/w1bb/w2gb/w2bb ushort 4 x 2048 float slots [6000640 .. 6008832)
//   zp        fp32   [6008832  .. 6008896)
// ---------------------------------------------------------------------------
extern "C" void kernel_launch(void* const* d_in, const int* in_sizes, int n_in,
                              void* d_out, int out_size, void* d_ws, size_t ws_size,
                              hipStream_t stream) {
  const float* x     = (const float*)d_in[0];
  const float* inter = (const float*)d_in[1];
  const float* w_off = (const float*)d_in[2];
  const float* b_off = (const float*)d_in[3];
  const float* w_dcn = (const float*)d_in[4];
  const float* wg1   = (const float*)d_in[5];
  const float* wg2   = (const float*)d_in[6];
  const float* wb1   = (const float*)d_in[7];
  const float* wb2   = (const float*)d_in[8];
  float* out = (float*)d_out;

  float* ws        = (float*)d_ws;
  ushort* x_clh    = (ushort*)ws;
  ushort* inter_clh= (ushort*)(ws + 2097152);
  ushort* wfb      = (ushort*)(ws + 5963776);
  ushort* wdT      = (ushort*)(ws + 5982208);
  ushort* w1gb     = (ushort*)(ws + 6000640);
  ushort* w1bb     = (ushort*)(ws + 6002688);
  ushort* w2gb     = (ushort*)(ws + 6004736);
  ushort* w2bb     = (ushort*)(ws + 6006784);
  float* zp        = ws + 6008832;

  // Prep: channels-last bf16 inputs + all packed weights + zero page.
  k_prep<<<1376, 256, 0, stream>>>(x, inter, w_off, w_dcn, wg1, wb1, wg2, wb2,
                                   x_clh, inter_clh, wfb, wdT,
                                   w1gb, w1bb, w2gb, w2bb, zp);

  // Fully fused conv + SFT + DCN.
  k_omega<<<2048, 256, 0, stream>>>(x, x_clh, inter_clh, b_off, wfb, wdT,
                                    w1gb, w1bb, w2gb, w2bb,
                                    (const ushort*)zp, out);
}

// Round 4
// 204.051 us; speedup vs baseline: 1.0404x; 1.0404x over previous
//
#include <hip/hip_runtime.h>
#include <hip/hip_bf16.h>
#include <math.h>

#define BB 4
#define CC 64
#define HH 128
#define WW 128
#define HW (HH*WW)          // 16384
#define NPIX (BB*HW)        // 65536

typedef __attribute__((ext_vector_type(8))) short short8;   // 8 bf16
typedef __attribute__((ext_vector_type(4))) float f32x4;

__device__ __forceinline__ float bf2f(ushort u) {
  union { unsigned u; float f; } v; v.u = ((unsigned)u) << 16; return v.f;
}
__device__ __forceinline__ ushort f2bf(float f) {
  __hip_bfloat16 h = __float2bfloat16(f); return *(ushort*)&h;
}

// ---------------------------------------------------------------------------
// Prep (unchanged): NCHW fp32 -> channels-last bf16 + weights.
// ---------------------------------------------------------------------------
__global__ __launch_bounds__(256) void k_prep(
    const float* __restrict__ x, const float* __restrict__ inter,
    const float* __restrict__ w_off, const float* __restrict__ w_dcn,
    const float* __restrict__ wg1, const float* __restrict__ wb1,
    const float* __restrict__ wg2, const float* __restrict__ wb2,
    ushort* __restrict__ x_clh, ushort* __restrict__ inter_clh,
    ushort* __restrict__ wfb, ushort* __restrict__ wdT,
    ushort* __restrict__ w1gb, ushort* __restrict__ w1bb,
    ushort* __restrict__ w2gb, ushort* __restrict__ w2bb,
    float* __restrict__ zp) {
  __shared__ __align__(16) float tile[64 * 128];   // 32 KiB, xor-swizzled
  int blk = blockIdx.x;
  int tid = threadIdx.x;
  if (blk < 1024) {
    int sel = blk >> 9;
    int bh = blk & 511;
    int b = bh >> 7, h = bh & 127;
    const float* src = sel ? inter : x;
    ushort* dst = sel ? inter_clh : x_clh;
    const float* sp = src + (size_t)(b * 64) * HW + h * WW;
#pragma unroll
    for (int it = 0; it < 8; ++it) {
      int idx = it * 256 + tid;
      int c = idx >> 5, wq = idx & 31;
      float4 v = *(const float4*)(sp + (size_t)c * HW + wq * 4);
      int s = (c >> 3) & 7;
      *(float4*)(&tile[c * 128 + ((wq ^ s) << 2)]) = v;
    }
    __syncthreads();
    ushort* dp = dst + ((size_t)b * HW + h * WW) * 64;
#pragma unroll
    for (int it = 0; it < 4; ++it) {
      int idx = it * 256 + tid;
      int w = idx >> 3, c8 = idx & 7;
      short8 outv;
#pragma unroll
      for (int j = 0; j < 8; ++j) {
        int c = c8 * 8 + j;
        int sl = (w >> 2) ^ c8;
        float f = tile[c * 128 + (sl << 2) + (w & 3)];
        outv[j] = (short)f2bf(f);
      }
      *(short8*)(dp + (size_t)w * 64 + c8 * 8) = outv;
    }
  } else if (blk < 1168) {
    int i = (blk - 1024) * 256 + tid;
    if (i < 64) zp[i] = 0.f;
    if (i < 9 * 32 * 128) {
      int tap = i >> 12, rem = i & 4095, m = rem >> 7, c = rem & 127;
      float v = (m < 27) ? w_off[(size_t)(m * 128 + c) * 9 + tap] : 0.f;
      wfb[i] = f2bf(v);
    }
  } else if (blk < 1312) {
    int i = (blk - 1168) * 256 + tid;
    if (i < 64 * 64 * 9) {
      int o = i / 576, rem = i % 576, k = rem >> 6, c = rem & 63;
      wdT[i] = f2bf(w_dcn[(o * 64 + c) * 9 + k]);
    }
  } else {
    int i = (blk - 1312) * 256 + tid;   // 0..16383
    int m = i >> 12, j = i & 4095;
    const float* src = (m == 0) ? wg1 : (m == 1) ? wb1 : (m == 2) ? wg2 : wb2;
    ushort* dst = (m == 0) ? w1gb : (m == 1) ? w1bb : (m == 2) ? w2gb : w2bb;
    dst[j] = f2bf(src[j]);
  }
}

// ---------------------------------------------------------------------------
// OMEGA v4: v3.1 structure with register starvation fixed.
//  - __launch_bounds__(256, 6): ~85-VGPR budget -> NO spills (round-3's
//    (256,8) clamp forced <=64 total regs -> 64 B/thread scratch spill,
//    +33 MB HBM writes, 83->131 us). 6 blocks/CU via LDS 19584.
//  - phase-6 `it` loop re-unrolled: 12 gather loads batched in flight
//    (registers exist again). chunk/ky loops stay rolled (icache).
//  - workspace compacted 24 MB -> ~17 MB (probes reset-poison cost).
// LDS layout (shorts; 9792 shorts = 19584 B):
//   [0,6272)     S  32px x 196 (phase 6)   | Sg[0,2304) Sb[2304,4608) (ph 3-4)
//   [6272,6848)  cycx packed int  (ph 5-6)
//   [6848,7424)  cwy f32          (ph 5-6)
//   [7424,8000)  cwx f32          (ph 5-6)
//   [8000,9782)  oml f32 27x33    (ph 2-6; rows 18-26 become sigmoid(m))
// ---------------------------------------------------------------------------
#define SPITCH 196   // shorts per pixel row in gather buffer S
#define NPX 32       // pixels per block
#define FPX 72       // shorts per px row in Sg/Sb

__global__ __launch_bounds__(256, 6) void k_omega(
    const float* __restrict__ x, const ushort* __restrict__ x_clh,
    const ushort* __restrict__ inter_clh,
    const float* __restrict__ b_off, const ushort* __restrict__ wfb,
    const ushort* __restrict__ wdT,
    const ushort* __restrict__ w1gb, const ushort* __restrict__ w1bb,
    const ushort* __restrict__ w2gb, const ushort* __restrict__ w2bb,
    const ushort* __restrict__ zp16, float* __restrict__ out) {
  __shared__ __align__(16) ushort LDSB[9792];          // 19584 B
  ushort* S  = LDSB;                                    // phase 6
  ushort* Sg = LDSB;                                    // phases 3-4
  ushort* Sb = LDSB + NPX * FPX;                        // 2304..4608
  int*   cycx = (int*)(LDSB + 6272);                    // 288 packed coords
  float* cwy  = (float*)(LDSB + 6848);
  float* cwx  = (float*)(LDSB + 7424);
  float* oml  = (float*)(LDSB + 8000);                  // 27 x 33 f32

  int tid = threadIdx.x;
  int wave = tid >> 6, lane = tid & 63;
  int quad = lane >> 4, col = lane & 15;
  int rr = lane >> 3, g = lane & 7;
  // XCD-local swizzle: 2048 blocks, 8 XCDs -> each XCD owns 256 consecutive
  // work ids (same-b, adjacent-h rows share gather/conv panels in its L2).
  int bid = blockIdx.x;
  int wid = (bid & 7) * 256 + (bid >> 3);
  int pg0 = wid * NPX;
  int b = pg0 >> 14, hw0 = pg0 & 16383;
  int h = hw0 >> 7, w0 = hw0 & 127;
  int pt = wave >> 1, mt = wave & 1;
  int o_base = __builtin_amdgcn_readfirstlane(wave * 16);

  // ---- phase 2: conv MFMAs, B-frags direct from global (no LDS halo) ----
  f32x4 accx = {0.f, 0.f, 0.f, 0.f}, acci = {0.f, 0.f, 0.f, 0.f};
  {
    const ushort* wb0 = wfb + (size_t)(mt * 16 + col) * 128 + quad * 8;
    int pxcol = pt * 16 + col;
    unsigned bbase = (unsigned)b * HW;
#pragma unroll 1
    for (int ky = 0; ky < 3; ++ky) {
      int hs = h + ky - 1;
      bool oky = (unsigned)hs < 128u;
      int rowb = hs << 7;
#pragma unroll
      for (int kx = 0; kx < 3; ++kx) {
        int ws = w0 + pxcol + kx - 1;
        bool ok = oky && ((unsigned)ws < 128u);
        long long poff = (long long)(int)(bbase + rowb + ws) * 64;
        // per-lane channel slice: ks*32 + quad*8 (zp page 128 zero shorts)
        const ushort* bx = (ok ? x_clh + poff : zp16) + quad * 8;
        const ushort* bi = (ok ? inter_clh + poff : zp16) + quad * 8;
        const ushort* wt = wb0 + (size_t)(ky * 3 + kx) * 4096;
#pragma unroll
        for (int ks = 0; ks < 2; ++ks) {
          short8 a0 = *(const short8*)(wt + ks * 32);
          short8 b0 = *(const short8*)(bx + ks * 32);
          accx = __builtin_amdgcn_mfma_f32_16x16x32_bf16(a0, b0, accx, 0, 0, 0);
          short8 a1 = *(const short8*)(wt + 64 + ks * 32);
          short8 b1 = *(const short8*)(bi + ks * 32);
          acci = __builtin_amdgcn_mfma_f32_16x16x32_bf16(a1, b1, acci, 0, 0, 0);
        }
      }
    }
  }
  // om -> LDS (consumed in phase 5, after B1).
#pragma unroll
  for (int r = 0; r < 4; ++r) {
    int o = mt * 16 + quad * 4 + r;
    if (o < 27) oml[o * 33 + pt * 16 + col] = accx[r] + acci[r];
  }

  // ---- phase 3: SFT stage A -> Sg/Sb ----
  f32x4 ag[2], ab[2];
#pragma unroll
  for (int nt = 0; nt < 2; ++nt) {
    ag[nt] = (f32x4){0.f, 0.f, 0.f, 0.f};
    ab[nt] = (f32x4){0.f, 0.f, 0.f, 0.f};
  }
#pragma unroll
  for (int ks = 0; ks < 2; ++ks) {
    short8 a_g = *(const short8*)(w1gb + (size_t)(o_base + col) * 64 + ks * 32 + quad * 8);
    short8 a_b = *(const short8*)(w1bb + (size_t)(o_base + col) * 64 + ks * 32 + quad * 8);
#pragma unroll
    for (int nt = 0; nt < 2; ++nt) {
      short8 bf = *(const short8*)(inter_clh + (size_t)(pg0 + nt * 16 + col) * 64 + ks * 32 + quad * 8);
      ag[nt] = __builtin_amdgcn_mfma_f32_16x16x32_bf16(a_g, bf, ag[nt], 0, 0, 0);
      ab[nt] = __builtin_amdgcn_mfma_f32_16x16x32_bf16(a_b, bf, ab[nt], 0, 0, 0);
    }
  }
#pragma unroll
  for (int nt = 0; nt < 2; ++nt) {
    int px = nt * 16 + col;
    ushort pkg[4], pkb[4];
#pragma unroll
    for (int r = 0; r < 4; ++r) {
      float vg = ag[nt][r]; vg = vg >= 0.f ? vg : 0.1f * vg;
      float vb = ab[nt][r]; vb = vb >= 0.f ? vb : 0.1f * vb;
      pkg[r] = f2bf(vg); pkb[r] = f2bf(vb);
    }
    *(uint2*)(&Sg[px * FPX + o_base + quad * 4]) = *(uint2*)pkg;
    *(uint2*)(&Sb[px * FPX + o_base + quad * 4]) = *(uint2*)pkb;
  }
  __syncthreads();   // B1: oml + Sg/Sb visible

  // ---- phase 4: SFT stage B; fold gamma/beta+x into epilogue vector ev ----
  f32x4 gg[2], gb[2];
#pragma unroll
  for (int nt = 0; nt < 2; ++nt) {
    gg[nt] = (f32x4){0.f, 0.f, 0.f, 0.f};
    gb[nt] = (f32x4){0.f, 0.f, 0.f, 0.f};
  }
#pragma unroll
  for (int ks = 0; ks < 2; ++ks) {
    short8 a_g = *(const short8*)(w2gb + (size_t)(o_base + col) * 64 + ks * 32 + quad * 8);
    short8 a_b = *(const short8*)(w2bb + (size_t)(o_base + col) * 64 + ks * 32 + quad * 8);
#pragma unroll
    for (int nt = 0; nt < 2; ++nt) {
      short8 bgf = *(const short8*)(Sg + (nt * 16 + col) * FPX + ks * 32 + quad * 8);
      short8 bbf = *(const short8*)(Sb + (nt * 16 + col) * FPX + ks * 32 + quad * 8);
      gg[nt] = __builtin_amdgcn_mfma_f32_16x16x32_bf16(a_g, bgf, gg[nt], 0, 0, 0);
      gb[nt] = __builtin_amdgcn_mfma_f32_16x16x32_bf16(a_b, bbf, gb[nt], 0, 0, 0);
    }
  }
  float ev[2][4];
#pragma unroll
  for (int nt = 0; nt < 2; ++nt)
#pragma unroll
    for (int r = 0; r < 4; ++r) {
      int o = o_base + quad * 4 + r;
      float xv = x[(size_t)(b * 64 + o) * HW + hw0 + nt * 16 + col];
      ev[nt][r] = xv + xv * gg[nt][r] + gb[nt][r];
    }

  // ---- phase 5: coords (packed) + sigmoid(m) in-place in oml ----
  // Writes coord region + oml m-rows only; disjoint from Sg/Sb phase-4 reads.
  for (int i = tid; i < 9 * NPX; i += 256) {
    int k = i >> 5, p = i & 31;
    float dy = oml[k * 33 + p] + b_off[k];
    float dx = oml[(9 + k) * 33 + p] + b_off[9 + k];
    float mz = oml[(18 + k) * 33 + p] + b_off[18 + k];
    float py = (float)(h + (k / 3) - 1) + dy;
    float px = (float)(w0 + p + (k % 3) - 1) + dx;
    float y0f = floorf(py), x0f = floorf(px);
    int iy = (int)y0f, ix = (int)x0f;
    cycx[i] = (iy & 0xffff) | (ix << 16);
    cwy[i] = py - y0f;
    cwx[i] = px - x0f;
    oml[(18 + k) * 33 + p] = 1.f / (1.f + __expf(-mz));
  }

  f32x4 acc[2];
  acc[0] = (f32x4){0.f, 0.f, 0.f, 0.f};
  acc[1] = (f32x4){0.f, 0.f, 0.f, 0.f};

  const ushort* bp = x_clh + (size_t)b * HW * 64;
  int p = wave * 8 + rr;

  // ---- phase 6: gather + MFMA chunks (chunk rolled, it unrolled) ----
#pragma unroll 1
  for (int chunk = 0; chunk < 3; ++chunk) {
    __syncthreads();   // chunk 0: coords ready + phase-4 Sg/Sb reads done
#pragma unroll
    for (int it = 0; it < 3; ++it) {
      int k = chunk * 3 + it;
      int idx = k * 32 + p;
      int v = cycx[idx];
      int y0 = (int)(short)(v & 0xffff);
      int x0 = v >> 16;
      float wy = cwy[idx], wx = cwx[idx];
      float m = oml[(18 + k) * 33 + p];
      bool yok0 = (unsigned)y0 < 128u, yok1 = (unsigned)(y0 + 1) < 128u;
      bool xok0 = (unsigned)x0 < 128u, xok1 = (unsigned)(x0 + 1) < 128u;
      const ushort* r0 = bp + ((size_t)(int)((y0 << 7) + x0)) * 64 + g * 8;
      const ushort* r1 = r0 + (size_t)WW * 64;
      short8 s00 = *(const short8*)((yok0 && xok0) ? r0 : zp16);
      short8 s01 = *(const short8*)((yok0 && xok1) ? (r0 + 64) : zp16);
      short8 s10 = *(const short8*)((yok1 && xok0) ? r1 : zp16);
      short8 s11 = *(const short8*)((yok1 && xok1) ? (r1 + 64) : zp16);
      short8 outv;
#pragma unroll
      for (int j = 0; j < 8; ++j) {
        float v00 = bf2f((ushort)s00[j]), v01 = bf2f((ushort)s01[j]);
        float v10 = bf2f((ushort)s10[j]), v11 = bf2f((ushort)s11[j]);
        float top = v00 + (v01 - v00) * wx;
        float bot = v10 + (v11 - v10) * wx;
        float val = top + (bot - top) * wy;
        outv[j] = (short)f2bf(val * m);
      }
      *(short8*)(&S[p * SPITCH + it * 64 + g * 8]) = outv;
    }
    __syncthreads();
    const ushort* wrow = wdT + (size_t)(o_base + col) * 576 + chunk * 192 + quad * 8;
    const ushort* srow = S + quad * 8;
#pragma unroll
    for (int ks = 0; ks < 6; ++ks) {
      short8 a = *(const short8*)(wrow + ks * 32);
#pragma unroll
      for (int nt = 0; nt < 2; ++nt) {
        short8 bf = *(const short8*)(srow + (nt * 16 + col) * SPITCH + ks * 32);
        acc[nt] = __builtin_amdgcn_mfma_f32_16x16x32_bf16(a, bf, acc[nt], 0, 0, 0);
      }
    }
  }

  // ---- phase 7: epilogue: out = ev + dcn (single write) ----
#pragma unroll
  for (int nt = 0; nt < 2; ++nt) {
#pragma unroll
    for (int r = 0; r < 4; ++r) {
      int o = o_base + quad * 4 + r;
      size_t idx = (size_t)(b * 64 + o) * HW + hw0 + nt * 16 + col;
      out[idx] = ev[nt][r] + acc[nt][r];
    }
  }
}

// ---------------------------------------------------------------------------
// Workspace plan (float slots), COMPACTED to ~17 MB (was 24 MB with a dead
// 7 MB gap; probes whether harness reset/poison cost scales with ws span):
//   x_clh     ushort [0        .. 2097152)
//   inter_clh ushort [2097152  .. 4194304)
//   wfb       ushort [4194304  .. 4212736)
//   wdT       ushort [4212736  .. 4231168)
//   w1gb/w1bb/w2gb/w2bb ushort 4 x 2048 float slots [4231168 .. 4239360)
//   zp        fp32   [4239360  .. 4239424)
// ---------------------------------------------------------------------------
extern "C" void kernel_launch(void* const* d_in, const int* in_sizes, int n_in,
                              void* d_out, int out_size, void* d_ws, size_t ws_size,
                              hipStream_t stream) {
  const float* x     = (const float*)d_in[0];
  const float* inter = (const float*)d_in[1];
  const float* w_off = (const float*)d_in[2];
  const float* b_off = (const float*)d_in[3];
  const float* w_dcn = (const float*)d_in[4];
  const float* wg1   = (const float*)d_in[5];
  const float* wg2   = (const float*)d_in[6];
  const float* wb1   = (const float*)d_in[7];
  const float* wb2   = (const float*)d_in[8];
  float* out = (float*)d_out;

  float* ws        = (float*)d_ws;
  ushort* x_clh    = (ushort*)ws;
  ushort* inter_clh= (ushort*)(ws + 2097152);
  ushort* wfb      = (ushort*)(ws + 4194304);
  ushort* wdT      = (ushort*)(ws + 4212736);
  ushort* w1gb     = (ushort*)(ws + 4231168);
  ushort* w1bb     = (ushort*)(ws + 4233216);
  ushort* w2gb     = (ushort*)(ws + 4235264);
  ushort* w2bb     = (ushort*)(ws + 4237312);
  float* zp        = ws + 4239360;

  // Prep: channels-last bf16 inputs + all packed weights + zero page.
  k_prep<<<1376, 256, 0, stream>>>(x, inter, w_off, w_dcn, wg1, wb1, wg2, wb2,
                                   x_clh, inter_clh, wfb, wdT,
                                   w1gb, w1bb, w2gb, w2bb, zp);

  // Fully fused conv + SFT + DCN.
  k_omega<<<2048, 256, 0, stream>>>(x, x_clh, inter_clh, b_off, wfb, wdT,
                                    w1gb, w1bb, w2gb, w2bb,
                                    (const ushort*)zp, out);
}